// Round 1
// baseline (14935.172 us; speedup 1.0000x reference)
//
#include <hip/hip_runtime.h>
#include <stdint.h>

#define BB 512
#define TT 256
#define FF 128
#define HH 256
#define G4 1024   // 4*H
#define K2 512    // gates K: 128 c_c + 128 m + 256 h
#define NBLK 256
#define EPSL 1e-9f

// ws layout (bytes)
#define OFF_WDHT 0            // bf16 [128][256]  (k-major, out contiguous)
#define OFF_WHT  65536        // bf16 [256][128]
#define OFF_WFT  131072       // bf16 [128][128]  diag pre-zeroed
#define OFF_WCT  163840       // bf16 [256][128]
#define OFF_W2T  229376       // bf16 [512][1024] rows 0..255=Wih cols, 256..511=Whh cols
#define OFF_MSUM 1277952      // f32 [256]
#define OFF_PART 1278976      // f32 [3][256][256]  (loss_i, t, blk)

__device__ __forceinline__ float bf2f(uint16_t u) {
    return __uint_as_float(((uint32_t)u) << 16);
}
__device__ __forceinline__ uint16_t f2bf(float v) {
    uint32_t u = __float_as_uint(v);
    uint32_t r = (u + 0x7fffu + ((u >> 16) & 1u)) >> 16;  // RNE
    return (uint16_t)r;
}
__device__ __forceinline__ float sigm(float x) { return 1.f / (1.f + expf(-x)); }

// ---------------- prep: convert weights to transposed bf16 in ws ----------------
__global__ void prep_weights(const float* __restrict__ Wdh, const float* __restrict__ Wh,
                             const float* __restrict__ Wf, const float* __restrict__ Wc,
                             const float* __restrict__ Wih, const float* __restrict__ Whh,
                             uint16_t* __restrict__ wsu) {
    const int total = 638976;
    for (int i = blockIdx.x * blockDim.x + threadIdx.x; i < total; i += gridDim.x * blockDim.x) {
        float v; int dst;
        if (i < 32768) {            // WdhT[k][j] = Wdh[j][k], Wdh [256,128]
            int o = i, k = o >> 8, j = o & 255;
            v = Wdh[j * 128 + k]; dst = (OFF_WDHT / 2) + o;
        } else if (i < 65536) {     // WhT[k][f] = Wh[f][k], Wh [128,256]
            int o = i - 32768, k = o >> 7, f = o & 127;
            v = Wh[f * 256 + k]; dst = (OFF_WHT / 2) + o;
        } else if (i < 81920) {     // WfT[k][f] = Wf[f][k] masked diag, Wf [128,128]
            int o = i - 65536, k = o >> 7, f = o & 127;
            v = (k == f) ? 0.f : Wf[f * 128 + k]; dst = (OFF_WFT / 2) + o;
        } else if (i < 114688) {    // WcT[k][f] = Wc[f][k], Wc [128,256]
            int o = i - 81920, k = o >> 7, f = o & 127;
            v = Wc[f * 256 + k]; dst = (OFF_WCT / 2) + o;
        } else {                    // W2T[k][g]: k<256 -> Wih[g][k], else Whh[g][k-256]
            int o = i - 114688, k = o >> 10, g = o & 1023;
            v = (k < 256) ? Wih[g * 256 + k] : Whh[g * 256 + (k - 256)];
            dst = (OFF_W2T / 2) + o;
        }
        wsu[dst] = f2bf(v);
    }
}

// ---------------- msum[t] = sum over B,F of mask[:,t,:] ----------------
__global__ void msum_kernel(const float* __restrict__ mask, float* __restrict__ msum) {
    int t = blockIdx.x;
    float s = 0.f;
    for (int i = threadIdx.x; i < BB * FF; i += 256) {
        int b = i >> 7, f = i & 127;
        s += mask[((long)b * TT + t) * FF + f];
    }
    __shared__ float red[4];
    for (int off = 32; off; off >>= 1) s += __shfl_down(s, off);
    if ((threadIdx.x & 63) == 0) red[threadIdx.x >> 6] = s;
    __syncthreads();
    if (threadIdx.x == 0) msum[t] = red[0] + red[1] + red[2] + red[3];
}

// ---------------- main sequential scan: 256 blocks x 2 rows ----------------
__launch_bounds__(256)
__global__ void rits_main(const float* __restrict__ values, const float* __restrict__ mask,
                          const float* __restrict__ deltas,
                          const float* __restrict__ bdh, const float* __restrict__ Wdx,
                          const float* __restrict__ bdx, const float* __restrict__ bh,
                          const float* __restrict__ bf_, const float* __restrict__ bc_,
                          const float* __restrict__ bih, const float* __restrict__ bhh,
                          const uint16_t* __restrict__ wsu,
                          float* __restrict__ part, float* __restrict__ out_imp) {
    __shared__ float h_lds[2 * HH];
    __shared__ float x_lds[2 * FF], m_lds[2 * FF], d_lds[2 * FF];
    __shared__ float gx_lds[2 * FF];
    __shared__ float xh_lds[2 * FF], xc_lds[2 * FF];
    __shared__ float act_lds[2 * K2];
    __shared__ float wred[3][4];

    const int j = threadIdx.x;
    const int blk = blockIdx.x;
    const int r0 = blk * 2;
    const int f = j & 127;
    const int rr = j >> 7;

    const uint16_t* WdhT = wsu + OFF_WDHT / 2;
    const uint16_t* WhT  = wsu + OFF_WHT / 2;
    const uint16_t* WfT  = wsu + OFF_WFT / 2;
    const uint16_t* WcT  = wsu + OFF_WCT / 2;
    const uint16_t* W2T  = wsu + OFF_W2T / 2;

    // hoisted per-thread constants
    const float c_bdh = bdh[j];
    const float c_bh = bh[f], c_bf = bf_[f], c_bc = bc_[f], c_bdx = bdx[f];
    const float c_wdx = Wdx[f * FF + f];
    const float bg0 = bih[0 * HH + j] + bhh[0 * HH + j];
    const float bg1 = bih[1 * HH + j] + bhh[1 * HH + j];
    const float bg2 = bih[2 * HH + j] + bhh[2 * HH + j];
    const float bg3 = bih[3 * HH + j] + bhh[3 * HH + j];

    float cst0 = 0.f, cst1 = 0.f;
    h_lds[j] = 0.f; h_lds[HH + j] = 0.f;
    __syncthreads();

    for (int t = 0; t < TT; ++t) {
        // ---- a: stage x, m, d + gamma_x ----
        {
            long src = ((long)(r0 + rr) * TT + t) * FF + f;
            float xv = values[src], mv = mask[src], dv = deltas[src];
            x_lds[j] = xv; m_lds[j] = mv; d_lds[j] = dv;
            gx_lds[j] = expf(-fmaxf(dv * c_wdx + c_bdx, 0.f));
        }
        __syncthreads();  // S1

        // ---- b: gamma_h, scale h, stage act h-part ----
        {
            float g0 = c_bdh, g1 = c_bdh;
            #pragma unroll 4
            for (int k = 0; k < FF; ++k) {
                float w = bf2f(WdhT[k * HH + j]);
                g0 = fmaf(d_lds[k], w, g0);
                g1 = fmaf(d_lds[FF + k], w, g1);
            }
            float hv0 = h_lds[j]      * expf(-fmaxf(g0, 0.f));
            float hv1 = h_lds[HH + j] * expf(-fmaxf(g1, 0.f));
            h_lds[j] = hv0; h_lds[HH + j] = hv1;
            act_lds[256 + j] = hv0;
            act_lds[K2 + 256 + j] = hv1;
        }
        __syncthreads();  // S2

        const float xv = x_lds[j], mv = m_lds[j];
        float acc1, acc2, acc3;
        float xh;
        // ---- c: x_h = h @ Wh.T + bh ----
        {
            float s = c_bh;
            const float* hrow = h_lds + rr * HH;
            #pragma unroll 4
            for (int k = 0; k < HH; ++k)
                s = fmaf(hrow[k], bf2f(WhT[k * FF + f]), s);
            xh = s;
            acc1 = fabsf(s - xv) * mv;
            xh_lds[j] = s;
            xc_lds[j] = mv * xv + (1.f - mv) * s;
        }
        __syncthreads();  // S3

        // ---- d: z_h = x_c @ Wf_masked.T + bf ----
        float zh;
        {
            float s = c_bf;
            const float* xcrow = xc_lds + rr * FF;
            #pragma unroll 4
            for (int k = 0; k < FF; ++k)
                s = fmaf(xcrow[k], bf2f(WfT[k * FF + f]), s);
            zh = s;
            acc2 = fabsf(s - xv) * mv;
        }
        // ---- e: alpha, c_h, imputed, c_c, stage act cc/m ----
        {
            float s = c_bc;
            const float* gxrow = gx_lds + rr * FF;
            const float* mrow  = m_lds + rr * FF;
            #pragma unroll 4
            for (int k = 0; k < FF; ++k)
                s = fmaf(gxrow[k], bf2f(WcT[k * FF + f]), s);
            #pragma unroll 4
            for (int k = 0; k < FF; ++k)
                s = fmaf(mrow[k], bf2f(WcT[(FF + k) * FF + f]), s);
            float alpha = s;
            float ch = alpha * zh + (1.f - alpha) * xh;
            acc3 = fabsf(ch - xv) * mv;
            float cc = mv * xv + (1.f - mv) * ch;
            out_imp[((long)(r0 + rr) * TT + t) * FF + f] = cc; // == mask*x + (1-mask)*c_h
            act_lds[rr * K2 + f] = cc;
            act_lds[rr * K2 + FF + f] = mv;
        }
        // ---- loss partial reduce (per step) ----
        {
            float a1 = acc1, a2 = acc2, a3 = acc3;
            for (int off = 32; off; off >>= 1) {
                a1 += __shfl_down(a1, off);
                a2 += __shfl_down(a2, off);
                a3 += __shfl_down(a3, off);
            }
            if ((j & 63) == 0) {
                int w = j >> 6;
                wred[0][w] = a1; wred[1][w] = a2; wred[2][w] = a3;
            }
        }
        __syncthreads();  // S4 (covers act_lds + wred)
        if (j < 3) {
            float s = wred[j][0] + wred[j][1] + wred[j][2] + wred[j][3];
            part[((long)j * TT + t) * NBLK + blk] = s;
        }
        // ---- f: gates GEMV (K=512) + LSTM update ----
        {
            float gi0 = bg0, gf0 = bg1, gg0 = bg2, go0 = bg3;
            float gi1 = bg0, gf1 = bg1, gg1 = bg2, go1 = bg3;
            #pragma unroll 4
            for (int k = 0; k < K2; ++k) {
                float a0 = act_lds[k], a1 = act_lds[K2 + k];
                const uint16_t* wrow = W2T + (long)k * G4;
                float wi = bf2f(wrow[j]);
                float wf = bf2f(wrow[HH + j]);
                float wg = bf2f(wrow[2 * HH + j]);
                float wo = bf2f(wrow[3 * HH + j]);
                gi0 = fmaf(a0, wi, gi0); gi1 = fmaf(a1, wi, gi1);
                gf0 = fmaf(a0, wf, gf0); gf1 = fmaf(a1, wf, gf1);
                gg0 = fmaf(a0, wg, gg0); gg1 = fmaf(a1, wg, gg1);
                go0 = fmaf(a0, wo, go0); go1 = fmaf(a1, wo, go1);
            }
            cst0 = sigm(gf0) * cst0 + sigm(gi0) * tanhf(gg0);
            float h0n = sigm(go0) * tanhf(cst0);
            cst1 = sigm(gf1) * cst1 + sigm(gi1) * tanhf(gg1);
            float h1n = sigm(go1) * tanhf(cst1);
            h_lds[j] = h0n; h_lds[HH + j] = h1n;
        }
        // no sync needed: next-iter S1 orders h_lds/act_lds reuse
    }
}

// ---------------- finisher: assemble the two scalar losses ----------------
__global__ void finisher(const float* __restrict__ part, const float* __restrict__ msum,
                         float* __restrict__ out2) {
    int t = threadIdx.x;  // 256 threads == 256 timesteps
    float s1 = 0.f, s2 = 0.f, s3 = 0.f;
    const float* p1 = part + ((long)0 * TT + t) * NBLK;
    const float* p2 = part + ((long)1 * TT + t) * NBLK;
    const float* p3 = part + ((long)2 * TT + t) * NBLK;
    for (int b = 0; b < NBLK; ++b) { s1 += p1[b]; s2 += p2[b]; s3 += p3[b]; }
    float den = msum[t] + EPSL;
    float l12 = (s1 + s2) / den;
    float l3  = s3 / den;
    float xl = l12 + (float)(TT - t) * l3;  // l3_t counted (T-t) times in x_loss
    float ml = l3;
    __shared__ float r1[4], r2[4];
    for (int off = 32; off; off >>= 1) {
        xl += __shfl_down(xl, off);
        ml += __shfl_down(ml, off);
    }
    if ((t & 63) == 0) { r1[t >> 6] = xl; r2[t >> 6] = ml; }
    __syncthreads();
    if (t == 0) {
        float X = r1[0] + r1[1] + r1[2] + r1[3];
        float M = r2[0] + r2[1] + r2[2] + r2[3];
        out2[0] = X / (float)(TT * 3);
        out2[1] = M / (float)TT;
    }
}

extern "C" void kernel_launch(void* const* d_in, const int* in_sizes, int n_in,
                              void* d_out, int out_size, void* d_ws, size_t ws_size,
                              hipStream_t stream) {
    const float* values = (const float*)d_in[0];
    const float* mask   = (const float*)d_in[1];
    const float* deltas = (const float*)d_in[2];
    const float* Wdh = (const float*)d_in[3];
    const float* bdh = (const float*)d_in[4];
    const float* Wdx = (const float*)d_in[5];
    const float* bdx = (const float*)d_in[6];
    const float* Wh  = (const float*)d_in[7];
    const float* bh  = (const float*)d_in[8];
    const float* Wf  = (const float*)d_in[9];
    const float* bf_ = (const float*)d_in[10];
    const float* Wc  = (const float*)d_in[11];
    const float* bc_ = (const float*)d_in[12];
    const float* Wih = (const float*)d_in[13];
    const float* Whh = (const float*)d_in[14];
    const float* bih = (const float*)d_in[15];
    const float* bhh = (const float*)d_in[16];

    float* out = (float*)d_out;
    uint16_t* wsu = (uint16_t*)d_ws;
    float* msum = (float*)((char*)d_ws + OFF_MSUM);
    float* part = (float*)((char*)d_ws + OFF_PART);

    prep_weights<<<2496, 256, 0, stream>>>(Wdh, Wh, Wf, Wc, Wih, Whh, wsu);
    msum_kernel<<<TT, 256, 0, stream>>>(mask, msum);
    rits_main<<<NBLK, 256, 0, stream>>>(values, mask, deltas, bdh, Wdx, bdx,
                                        bh, bf_, bc_, bih, bhh, wsu, part, out);
    finisher<<<1, 256, 0, stream>>>(part, msum, out + (long)BB * TT * FF);
}